// Round 6
// baseline (288.271 us; speedup 1.0000x reference)
//
#include <hip/hip_runtime.h>
#include <math.h>

#define DELTA      0.04f
#define LOG_CLAMP  -100.0f
#define N          2048
#define ROWS_PER_BLOCK 4
#define BLOCK      256

// R3-R5 post-mortem: compiler insists on a depth-~5 load pipeline (VGPR=36),
// capping delivered BW at ~2.5 TB/s (latency-bound, VALUBusy ~9%). Fix:
// stage the anchor row via 16x __builtin_amdgcn_global_load_lds (1 KB each,
// zero data VGPRs, can't be serialized by the register allocator) into a
// per-wave 16 KB LDS region. 2 blocks/CU x 4 waves x 16 KB = 128 KB in
// flight per CU -- far above the ~25 KB Little's-law requirement for the
// 6.3 TB/s ceiling. Conf (1/3 of bytes) stays on the plain VGPR path and its
// exp/sum overlaps the anchor flight; __syncthreads drains vmcnt before the
// LDS argmin pass.
__device__ __forceinline__ void gl_lds16(const float4* g, float4* l) {
    __builtin_amdgcn_global_load_lds(
        (const __attribute__((address_space(1))) void*)g,
        (__attribute__((address_space(3))) void*)l, 16, 0, 0);
}

__global__ __launch_bounds__(BLOCK) void row_kernel(
    const float* __restrict__ anchors,   // B x N x 2
    const float* __restrict__ offsets,   // B x N x 2
    const float* __restrict__ conf,      // B x N
    const float* __restrict__ gt,        // B x 2
    float2* __restrict__ part)           // B x (ce, hu)
{
    const int wid  = threadIdx.x >> 6;
    const int lane = threadIdx.x & 63;
    const int b    = blockIdx.x * ROWS_PER_BLOCK + wid;

    const float4* __restrict__ arow4 = (const float4*)(anchors + (size_t)b * N * 2); // 1024 f4
    const float4* __restrict__ crow4 = (const float4*)(conf + (size_t)b * N);        // 512 f4
    const float2 g = ((const float2*)gt)[b];

    __shared__ float4 sA[ROWS_PER_BLOCK][1024];   // 64 KB: per-wave anchor row

    // ---- conf loads (plain; overlap with anchor staging) ----
    float4 C[8];
    #pragma unroll
    for (int k = 0; k < 8; ++k) C[k] = crow4[k * 64 + lane];

    // ---- anchors -> LDS: 16 async 1 KB copies, no VGPR round trip ----
    // HW semantics: uniform LDS base + lane*16; global addr per-lane.
    #pragma unroll
    for (int k = 0; k < 16; ++k)
        gl_lds16(arow4 + k * 64 + lane, &sA[wid][k * 64]);

    // ---- exp in place + sum while anchors fly ----
    float sume = 0.0f;
    #pragma unroll
    for (int k = 0; k < 8; ++k) {
        C[k].x = __expf(C[k].x);
        C[k].y = __expf(C[k].y);
        C[k].z = __expf(C[k].z);
        C[k].w = __expf(C[k].w);
        sume += (C[k].x + C[k].y) + (C[k].z + C[k].w);
    }
    #pragma unroll
    for (int off = 1; off < 64; off <<= 1)
        sume += __shfl_xor(sume, off, 64);
    const float inv = 1.0f / sume;

    __syncthreads();   // drains vmcnt(0): anchor LDS regions are complete

    // ---- argmin of squared distance from LDS ----
    float dmin = INFINITY;
    int   imin = 0;
    #pragma unroll
    for (int k = 0; k < 16; ++k) {
        const float4 a = sA[wid][k * 64 + lane];
        const int f = k * 64 + lane;            // float4 idx = point pair 2f,2f+1
        float dx, dy, d;
        dx = a.x - g.x; dy = a.y - g.y; d = dx * dx + dy * dy;
        if (d < dmin) { dmin = d; imin = 2 * f; }
        dx = a.z - g.x; dy = a.w - g.y; d = dx * dx + dy * dy;
        if (d < dmin) { dmin = d; imin = 2 * f + 1; }
    }
    #pragma unroll
    for (int off = 1; off < 64; off <<= 1) {
        const float d2 = __shfl_xor(dmin, off, 64);
        const int   i2 = __shfl_xor(imin, off, 64);
        if (d2 < dmin || (d2 == dmin && i2 < imin)) { dmin = d2; imin = i2; }
    }

    // ---- sum log(1-p): per-lane product + one hardware log ----
    float prod = 1.0f;
    #pragma unroll
    for (int k = 0; k < 8; ++k) {
        prod *= fmaf(-C[k].x, inv, 1.0f) * fmaf(-C[k].y, inv, 1.0f)
              * fmaf(-C[k].z, inv, 1.0f) * fmaf(-C[k].w, inv, 1.0f);
    }
    float slog = __logf(fmaxf(prod, 1e-37f));   // underflow guard; unreachable here
    #pragma unroll
    for (int off = 1; off < 64; off <<= 1)
        slog += __shfl_xor(slog, off, 64);

    if (lane == 0) {
        const int ci = imin;
        const float  cci = (conf + (size_t)b * N)[ci];                     // gather
        const float2 co  = ((const float2*)(offsets + (size_t)b * N * 2))[ci]; // gather
        const float4 ap  = sA[wid][ci >> 1];                               // from LDS
        const float cax = (ci & 1) ? ap.z : ap.x;
        const float cay = (ci & 1) ? ap.w : ap.y;

        const float p_ci = __expf(cci) * inv;
        const float logp = fmaxf(__logf(p_ci),        LOG_CLAMP);
        const float l1mp = fmaxf(__logf(1.0f - p_ci), LOG_CLAMP);
        const float ce = -(logp + (slog - l1mp));

        const float x0 = co.x - (g.x - cax);
        const float x1 = co.y - (g.y - cay);
        const float a0 = fabsf(x0);
        const float a1 = fabsf(x1);
        const float h0 = (a0 <= DELTA) ? 0.5f * x0 * x0 : DELTA * (a0 - 0.5f * DELTA);
        const float h1 = (a1 <= DELTA) ? 0.5f * x1 * x1 : DELTA * (a1 - 0.5f * DELTA);

        part[b] = make_float2(ce, h0 + h1);
    }
}

// Single-block deterministic final reduce (double accumulate), 1024 threads.
__global__ __launch_bounds__(1024) void reduce_kernel(
    const float2* __restrict__ part,
    float* __restrict__ out, int nrows)
{
    double ce = 0.0, hu = 0.0;
    for (int i = threadIdx.x; i < nrows; i += 1024) {
        const float2 p = part[i];
        ce += (double)p.x;
        hu += (double)p.y;
    }
    #pragma unroll
    for (int off = 32; off > 0; off >>= 1) {
        ce += __shfl_down(ce, off, 64);
        hu += __shfl_down(hu, off, 64);
    }
    __shared__ double sc[16], sh[16];
    const int wid = threadIdx.x >> 6, lane = threadIdx.x & 63;
    if (lane == 0) { sc[wid] = ce; sh[wid] = hu; }
    __syncthreads();
    if (threadIdx.x == 0) {
        double tce = 0.0, thu = 0.0;
        #pragma unroll
        for (int w = 0; w < 16; ++w) { tce += sc[w]; thu += sh[w]; }
        out[0] = (float)(tce + thu);
        out[1] = (float)tce;
        out[2] = (float)thu;
    }
}

extern "C" void kernel_launch(void* const* d_in, const int* in_sizes, int n_in,
                              void* d_out, int out_size, void* d_ws, size_t ws_size,
                              hipStream_t stream) {
    const float* anchors = (const float*)d_in[0];
    const float* offsets = (const float*)d_in[1];
    const float* conf    = (const float*)d_in[2];
    const float* gt      = (const float*)d_in[3];
    float* out = (float*)d_out;

    const int B = in_sizes[3] / 2;   // ground_truth is (B, 2)

    float2* part = (float2*)d_ws;    // B float2 partials

    row_kernel<<<B / ROWS_PER_BLOCK, BLOCK, 0, stream>>>(anchors, offsets, conf, gt, part);
    reduce_kernel<<<1, 1024, 0, stream>>>(part, out, B);
}